// Round 1
// baseline (376.366 us; speedup 1.0000x reference)
//
#include <hip/hip_runtime.h>

// BackWarp: dense bilinear backward warp.
// Strategy: flow ~ N(0,1) => query coords lie within +-8 px of (y,x) with
// probability ~1-6e-16. Stage image tile + 8px halo in LDS with coalesced
// 16B global_load_lds; do the 12 corner reads per pixel from LDS instead of
// divergent global gathers (the measured bottleneck: 36% HBM, 11% VALU,
// 80% occupancy => stalled on the divergent-gather L1/TA path).
// Per-pixel bounds check falls back to global gathers => unconditionally correct.

#define BW_B 16
#define BW_H 720
#define BW_W 1280
#define BW_C 3

#define TILE_W 64
#define TILE_H 8
#define HALO 8
#define SROWS (TILE_H + 2 * HALO + 1)   // 25 staged rows
#define SFLOATS 248                     // floats per staged row (62 float4)
#define S4_PER_ROW 62
#define NSLOT4 (SROWS * S4_PER_ROW)     // 1550 float4 slots
#define NSLOTF (SROWS * SFLOATS)        // 6200 floats = 24.8 KB

typedef float floatx2 __attribute__((ext_vector_type(2)));

#define GLB_AS __attribute__((address_space(1)))
#define LDS_AS __attribute__((address_space(3)))

__device__ __forceinline__ int clampi(int v, int lo, int hi) {
    return v < lo ? lo : (v > hi ? hi : v);
}

__device__ __forceinline__ void warp_px(
    const float* __restrict__ imgb,     // image base for this batch (fallback)
    const float* __restrict__ smem,     // staged tile
    int ylo, int xlo,
    floatx2 f, int x, int y, float* __restrict__ o) {
    const float qy = (float)y - f.x;
    const float qx = (float)x - f.y;

    float fy = floorf(qy);
    fy = fminf(fmaxf(fy, 0.0f), (float)(BW_H - 2));
    float fx = floorf(qx);
    fx = fminf(fmaxf(fx, 0.0f), (float)(BW_W - 2));
    const float ay = fminf(fmaxf(qy - fy, 0.0f), 1.0f);
    const float ax = fminf(fmaxf(qx - fx, 0.0f), 1.0f);
    const int iy = (int)fy;
    const int ix = (int)fx;

    const int jr = iy - ylo;            // staged row of top corners
    const int jc = ix - xlo;            // staged col (pixels)

    float tl0, tl1, tl2, tr0, tr1, tr2, bl0, bl1, bl2, br0, br1, br2;

    // need rows jr, jr+1 (jr <= SROWS-2) and floats 3*jc .. 3*jc+5 (jc <= 80)
    if (__builtin_expect((unsigned)jr <= (unsigned)(SROWS - 2) &&
                         (unsigned)jc <= 80u, 1)) {
        const float* L = smem + jr * SFLOATS + 3 * jc;
        tl0 = L[0];           tl1 = L[1];           tl2 = L[2];
        tr0 = L[3];           tr1 = L[4];           tr2 = L[5];
        bl0 = L[SFLOATS];     bl1 = L[SFLOATS + 1]; bl2 = L[SFLOATS + 2];
        br0 = L[SFLOATS + 3]; br1 = L[SFLOATS + 4]; br2 = L[SFLOATS + 5];
    } else {
        // |flow| > HALO: astronomically rare for N(0,1); correct global path.
        const float* __restrict__ p0 = imgb + (iy * BW_W + ix) * BW_C;
        const float* __restrict__ p1 = p0 + BW_W * BW_C;
        tl0 = p0[0]; tl1 = p0[1]; tl2 = p0[2];
        tr0 = p0[3]; tr1 = p0[4]; tr2 = p0[5];
        bl0 = p1[0]; bl1 = p1[1]; bl2 = p1[2];
        br0 = p1[3]; br1 = p1[4]; br2 = p1[5];
    }

    const float it0 = tl0 + ax * (tr0 - tl0);
    const float it1 = tl1 + ax * (tr1 - tl1);
    const float it2 = tl2 + ax * (tr2 - tl2);
    const float ib0 = bl0 + ax * (br0 - bl0);
    const float ib1 = bl1 + ax * (br1 - bl1);
    const float ib2 = bl2 + ax * (br2 - bl2);

    __builtin_nontemporal_store(it0 + ay * (ib0 - it0), o + 0);
    __builtin_nontemporal_store(it1 + ay * (ib1 - it1), o + 1);
    __builtin_nontemporal_store(it2 + ay * (ib2 - it2), o + 2);
}

__global__ __launch_bounds__(256, 6) void backwarp_kernel(
    const float* __restrict__ image,
    const float* __restrict__ flow,
    float* __restrict__ out) {
    __shared__ float smem[NSLOTF];

    const int tx = threadIdx.x;              // 0..63 = lane (wave == ty row)
    const int ty = threadIdx.y;              // 0..3  = wave id
    const int x0 = blockIdx.x * TILE_W;
    const int y0t = blockIdx.y * TILE_H;
    const int b = blockIdx.z;

    const int x = x0 + tx;
    const int ya = y0t + ty;
    const int yb = ya + 4;

    const float* __restrict__ imgb = image + (size_t)b * (BW_H * BW_W * BW_C);
    const unsigned base_b = (unsigned)b * (BW_H * BW_W);
    const unsigned i0 = base_b + (unsigned)ya * BW_W + (unsigned)x;
    const unsigned i1 = base_b + (unsigned)yb * BW_W + (unsigned)x;

    // flow: read-once stream -> nontemporal, issued early (hides under staging)
    const floatx2* __restrict__ fl = (const floatx2*)flow;
    const floatx2 f0 = __builtin_nontemporal_load(fl + i0);
    const floatx2 f1 = __builtin_nontemporal_load(fl + i1);

    const int ylo = y0t - HALO;
    const int xlo = x0 - HALO;

    // ---- stage [25 rows x 248 floats] halo tile into LDS ----
    const bool interior = (blockIdx.x >= 1) && (blockIdx.x <= (BW_W / TILE_W) - 2);
    if (interior) {
        // 3*xlo is a multiple of 4 for interior blocks -> 16B-aligned source
        const int rowoff = 3 * xlo;          // float offset of staged row start
        #pragma unroll
        for (int it = 0; it < 7; ++it) {
            const int s = it * 256 + ty * 64 + tx;
            if (s < NSLOT4) {
                const int r = s / S4_PER_ROW;
                const int c4 = s - r * S4_PER_ROW;
                const int rr = clampi(ylo + r, 0, BW_H - 1);
                const float* src = imgb + rr * (BW_W * BW_C) + rowoff + c4 * 4;
                const unsigned lbyte = (unsigned)(it * 256 + ty * 64) * 16u; // wave-uniform
                __builtin_amdgcn_global_load_lds(
                    (const GLB_AS void*)src,
                    (LDS_AS void*)((LDS_AS char*)smem + lbyte),
                    16, 0, 0);
            }
        }
    } else {
        // x-border blocks (2 of 20): per-float staging with column clamp
        #pragma unroll 1
        for (int it = 0; it < 25; ++it) {
            const int s = it * 256 + ty * 64 + tx;
            if (s < NSLOTF) {
                const int r = s / SFLOATS;
                const int k = s - r * SFLOATS;
                const int p = k / 3;
                const int ch = k - p * 3;
                const int rr = clampi(ylo + r, 0, BW_H - 1);
                const int cc = clampi(xlo + p, 0, BW_W - 1);
                const float* src = imgb + rr * (BW_W * BW_C) + cc * BW_C + ch;
                const unsigned lbyte = (unsigned)(it * 256 + ty * 64) * 4u; // wave-uniform
                __builtin_amdgcn_global_load_lds(
                    (const GLB_AS void*)src,
                    (LDS_AS void*)((LDS_AS char*)smem + lbyte),
                    4, 0, 0);
            }
        }
    }
    __syncthreads();

    warp_px(imgb, smem, ylo, xlo, f0, x, ya, out + (size_t)i0 * BW_C);
    warp_px(imgb, smem, ylo, xlo, f1, x, yb, out + (size_t)i1 * BW_C);
}

extern "C" void kernel_launch(void* const* d_in, const int* in_sizes, int n_in,
                              void* d_out, int out_size, void* d_ws, size_t ws_size,
                              hipStream_t stream) {
    const float* image = (const float*)d_in[0];
    const float* flow  = (const float*)d_in[1];
    float* out = (float*)d_out;

    dim3 block(TILE_W, TILE_H / 2, 1);                 // 64 x 4 = 256
    dim3 grid(BW_W / TILE_W, BW_H / TILE_H, BW_B);     // 20 x 90 x 16
    backwarp_kernel<<<grid, block, 0, stream>>>(image, flow, out);
}